// Round 6
// baseline (402.330 us; speedup 1.0000x reference)
//
#include <hip/hip_runtime.h>
#include <hip/hip_bf16.h>
#include <stdint.h>

static constexpr int ND = 8192;

typedef __attribute__((ext_vector_type(8))) short bf16x8;
typedef __attribute__((ext_vector_type(4))) float f32x4;

#define GLOBAL_AS __attribute__((address_space(1)))
#define LDS_AS __attribute__((address_space(3)))

__device__ __forceinline__ void gld_lds16(const void* g, void* l) {
    __builtin_amdgcn_global_load_lds((const GLOBAL_AS void*)g, (LDS_AS void*)l, 16, 0, 0);
}

__device__ __forceinline__ unsigned short f2bf(float x) {
    union { float f; uint32_t u; } v; v.f = x;
    uint32_t u = v.u;
    uint32_t r = (u + 0x7fffu + ((u >> 16) & 1u)) >> 16;
    return (unsigned short)r;
}

// ---------------- pre-pass 1: Aw[i][k] = (k>=i) ? bf16(A[i][k]) : 0 ----------------
__global__ void conv_a(const float* __restrict__ A, unsigned short* __restrict__ Aw) {
    uint32_t g = blockIdx.x * 256u + threadIdx.x;
    int i  = (int)(g >> 10);
    int k0 = (int)(g & 1023u) << 3;
    if (k0 + 8 <= (i & ~255)) return;          // never read: k < (i>>8)*256
    const float* src = A + (size_t)i * ND + k0;
    float4 lo = *(const float4*)src;
    float4 hi = *(const float4*)(src + 4);
    float vals[8] = {lo.x, lo.y, lo.z, lo.w, hi.x, hi.y, hi.z, hi.w};
    unsigned short out[8];
#pragma unroll
    for (int e = 0; e < 8; ++e) {
        int k = k0 + e;
        out[e] = (k >= i) ? f2bf(vals[e]) : (unsigned short)0;
    }
    *(uint4*)(Aw + (size_t)i * ND + k0) = *(const uint4*)out;
}

// ------------- pre-pass 2: Bt[j][k] = (k<=j) ? bf16(B[k][j]) : 0 (transpose) -------------
__global__ void conv_bt(const float* __restrict__ B, unsigned short* __restrict__ Bt) {
    __shared__ float tile[64][65];
    int tk = blockIdx.x, tj = blockIdx.y;
    int t = threadIdx.x;
    int k0 = tk * 64, j0 = tj * 64;

    if (k0 > j0 + 63) {                         // tile wholly above diagonal (k > j)
        if (tk >= ((tj >> 2) + 1) * 4) return;  // beyond the 256-block: never read
        int jl = t >> 4;
        int kl = (t & 15) * 4;
#pragma unroll
        for (int r = 0; r < 4; ++r) {
            int j = j0 + jl + r * 16;
            *(uint2*)(Bt + (size_t)j * ND + k0 + kl) = make_uint2(0u, 0u);
        }
        return;
    }
    {   // load: coalesced in j
        int kl  = t >> 4;
        int jl4 = (t & 15) * 4;
#pragma unroll
        for (int r = 0; r < 4; ++r) {
            int k = k0 + kl + r * 16;
            float4 v = *(const float4*)(B + (size_t)k * ND + j0 + jl4);
            tile[kl + r * 16][jl4 + 0] = v.x;
            tile[kl + r * 16][jl4 + 1] = v.y;
            tile[kl + r * 16][jl4 + 2] = v.z;
            tile[kl + r * 16][jl4 + 3] = v.w;
        }
    }
    __syncthreads();
    {   // store: coalesced in k
        int jl  = t >> 4;
        int kl4 = (t & 15) * 4;
#pragma unroll
        for (int r = 0; r < 4; ++r) {
            int j = j0 + jl + r * 16;
            unsigned short o[4];
#pragma unroll
            for (int e = 0; e < 4; ++e) {
                int k = k0 + kl4 + e;
                float v = tile[kl4 + e][jl + r * 16];
                o[e] = (k <= j) ? f2bf(v) : (unsigned short)0;
            }
            *(uint2*)(Bt + (size_t)j * ND + k0 + kl4) = *(const uint2*)o;
        }
    }
}

// ------ zero-fill strictly-lower 128x128 tiles NOT covered by diagonal 256-blocks ------
__global__ __launch_bounds__(256) void zero_lower(float* __restrict__ C) {
    int bid = blockIdx.x;                        // 0 .. 2015
    int ti = (int)((1.0f + sqrtf(8.0f * (float)bid + 1.0f)) * 0.5f);
    while (ti * (ti + 1) / 2 <= bid) ++ti;
    while (ti * (ti - 1) / 2 > bid) --ti;
    int tj = bid - ti * (ti - 1) / 2;            // ti in [1,63], tj < ti
    if ((ti >> 1) == (tj >> 1)) return;          // covered by diagonal 256-tile GEMM
    int t = threadIdx.x;
    float* base = C + (size_t)(ti * 128) * ND + tj * 128;
    float4 z = {0.f, 0.f, 0.f, 0.f};
#pragma unroll
    for (int it = 0; it < 16; ++it) {
        int row = it * 8 + (t >> 5);
        *(float4*)(base + (size_t)row * ND + (t & 31) * 4) = z;
    }
}

// ====== main GEMM: 256x256 tiles, 8-phase pipeline, persistent blocks (grid=256) ======
// XCD x (= bid%8, exact since all 256 blocks co-resident) owns a compile-time
// greedy-LPT set of tile-ROWS (max +1.7% work imbalance). All jobs of a row read
// nested subranges of the same <=4MB A panel -> concurrent same-XCD L2 hits.
// Within an XCD, jobs (rows big-first, tj descending = longest-first) are
// partitioned over the 32 CUs by prefix-midpoint chunking on K-tile cost; each
// block executes its contiguous chunk sequentially (A panel reuse per CU too).
#define BAR() __builtin_amdgcn_s_barrier()
#define WAIT_LGKM0() asm volatile("s_waitcnt lgkmcnt(0)" ::: "memory")
#define WAIT_VM4() asm volatile("s_waitcnt vmcnt(4)" ::: "memory")
#define WAIT_VM0() asm volatile("s_waitcnt vmcnt(0)" ::: "memory")
#define PRIO(x) __builtin_amdgcn_s_setprio(x)

#define LDA(BUF, MH) do { \
    _Pragma("unroll") for (int m_ = 0; m_ < 4; ++m_) \
    _Pragma("unroll") for (int kk_ = 0; kk_ < 2; ++kk_) \
        a_frag[m_][kk_] = *(const bf16x8*)(lds0 + (((BUF)*2 + 0)*2 + (MH))*8192 \
            + (a_lr + m_*16)*64 + (((kk_*4 + khi) ^ lanelo) << 3)); \
} while (0)

#define LDB(BUF, NH) do { \
    _Pragma("unroll") for (int n_ = 0; n_ < 2; ++n_) \
    _Pragma("unroll") for (int kk_ = 0; kk_ < 2; ++kk_) \
        b_frag[NH][n_][kk_] = *(const bf16x8*)(lds0 + (((BUF)*2 + 1)*2 + (NH))*8192 \
            + (b_lr + n_*16)*64 + (((kk_*4 + khi) ^ lanelo) << 3)); \
} while (0)

#define MM(MH, NH) do { \
    _Pragma("unroll") for (int kk_ = 0; kk_ < 2; ++kk_) \
    _Pragma("unroll") for (int m_ = 0; m_ < 4; ++m_) \
    _Pragma("unroll") for (int n_ = 0; n_ < 2; ++n_) \
        acc[(MH)*4 + m_][(NH)*2 + n_] = __builtin_amdgcn_mfma_f32_16x16x32_bf16( \
            a_frag[m_][kk_], b_frag[NH][n_][kk_], acc[(MH)*4 + m_][(NH)*2 + n_], 0, 0, 0); \
} while (0)

__global__ __launch_bounds__(512, 2) void gemm_tri8(const unsigned short* __restrict__ Aw,
                                                    const unsigned short* __restrict__ Bt,
                                                    float* __restrict__ C) {
    // greedy-LPT row->XCD assignment (work = 4*T(32-ti) K-tiles per row)
    static const signed char rows_tbl[8][5] = {
        {0, 15, 23, 27, 31}, {1, 14, 22, 25, -1}, {2, 13, 21, 24, -1},
        {3, 12, 20, 26, -1}, {4, 11, 19, 28, 30}, {5, 10, 18, 29, -1},
        {6, 9, 17, -1, -1},  {7, 8, 16, -1, -1}};
    static const int ktot_tbl[8] = {2968, 3000, 3028, 2976, 2964, 2968, 2988, 3044};

    int xcd = blockIdx.x & 7, slot = blockIdx.x >> 3;   // grid=256: mapping exact
    int ktot = ktot_tbl[xcd];

    __shared__ __align__(16) unsigned short lds[2][2][2][128][64];
    unsigned short* lds0 = &lds[0][0][0][0][0];

    int t = threadIdx.x;
    int lane = t & 63, w = t >> 6;
    int wr = w >> 2, wc = w & 3;
    int lanelo = lane & 7, khi = lane >> 4;
    int a_lr = wr * 64 + (lane & 15);
    int b_lr = wc * 32 + (lane & 15);
    int srow = w * 8 + (lane >> 3);
    int sg = ((lane & 7) ^ (lane >> 3)) * 8;
    unsigned short* sdst = lds0 + (w * 512 + lane * 8);

    int P = 0;                                   // prefix cost in K-tiles
    for (int r = 0; r < 5; ++r) {
        int tib = rows_tbl[xcd][r];
        if (tib < 0) break;
        for (int tjb = 31; tjb >= tib; --tjb) {
            int nkt = 4 * (tjb - tib + 1);
            int cu = (2 * P + nkt) * 16 / ktot;
            if (cu > 31) cu = 31;
            P += nkt;
            if (cu != slot) continue;

            // ---------------- one job: tile (tib, tjb), full K range ----------------
            int kstart = tib * 256;
            int nit = nkt >> 1;
            const unsigned short* gA = Aw + (size_t)(tib * 256 + srow) * ND + sg;
            const unsigned short* gB = Bt + (size_t)(tjb * 256 + srow) * ND + sg;

            auto STAGE = [&](int ab, int buf, int h, int ktg) {
                const unsigned short* g =
                    (ab ? gB : gA) + (size_t)(h * 128) * ND + (kstart + ktg * 64);
                unsigned short* l = sdst + ((buf * 2 + ab) * 2 + h) * 8192;
                gld_lds16(g, l);
                gld_lds16(g + (size_t)64 * ND, l + 4096);
            };

            f32x4 acc[8][4];
#pragma unroll
            for (int m = 0; m < 8; ++m)
#pragma unroll
                for (int n = 0; n < 4; ++n) acc[m][n] = (f32x4){0.f, 0.f, 0.f, 0.f};

            bf16x8 a_frag[4][2];
            bf16x8 b_frag[2][2][2];

            // prologue: kt0 fully + kt1 A0,B0 (leave kt1's 2 half-tiles in flight)
            STAGE(0, 0, 0, 0); STAGE(1, 0, 0, 0); STAGE(0, 0, 1, 0); STAGE(1, 0, 1, 0);
            STAGE(0, 1, 0, 1); STAGE(1, 1, 0, 1);
            WAIT_VM4();
            BAR();

            for (int I = 0; I < nit; ++I) {
                int k1 = 2 * I + 1, k2 = 2 * I + 2, k3 = 2 * I + 3;
                bool s23 = (k2 < nkt);

                LDA(0, 0); LDB(0, 0);
                STAGE(0, 1, 1, k1);
                BAR(); WAIT_LGKM0(); PRIO(1); MM(0, 0); PRIO(0); BAR();
                LDB(0, 1);
                STAGE(1, 1, 1, k1);
                BAR(); WAIT_LGKM0(); PRIO(1); MM(0, 1); PRIO(0); BAR();
                LDA(0, 1);
                if (s23) STAGE(0, 0, 0, k2);
                BAR(); WAIT_LGKM0(); PRIO(1); MM(1, 0); PRIO(0); BAR();
                if (s23) STAGE(1, 0, 0, k2);
                BAR(); PRIO(1); MM(1, 1); PRIO(0);
                if (s23) { WAIT_VM4(); } else { WAIT_VM0(); }
                BAR();
                LDA(1, 0); LDB(1, 0);
                if (s23) STAGE(0, 0, 1, k2);
                BAR(); WAIT_LGKM0(); PRIO(1); MM(0, 0); PRIO(0); BAR();
                LDB(1, 1);
                if (s23) STAGE(1, 0, 1, k2);
                BAR(); WAIT_LGKM0(); PRIO(1); MM(0, 1); PRIO(0); BAR();
                LDA(1, 1);
                if (s23) STAGE(0, 1, 0, k3);
                BAR(); WAIT_LGKM0(); PRIO(1); MM(1, 0); PRIO(0); BAR();
                if (s23) STAGE(1, 1, 0, k3);
                BAR(); PRIO(1); MM(1, 1); PRIO(0); WAIT_VM4(); BAR();
            }

            // epilogue: C/D layout col=lane&15, row=(lane>>4)*4+e
#pragma unroll
            for (int mh = 0; mh < 2; ++mh)
#pragma unroll
                for (int m = 0; m < 4; ++m)
#pragma unroll
                    for (int nh = 0; nh < 2; ++nh)
#pragma unroll
                        for (int n = 0; n < 2; ++n) {
                            f32x4 v = acc[mh * 4 + m][nh * 2 + n];
                            int row0 = tib * 256 + mh * 128 + wr * 64 + m * 16 + (lane >> 4) * 4;
                            int col  = tjb * 256 + nh * 128 + wc * 32 + n * 16 + (lane & 15);
#pragma unroll
                            for (int e = 0; e < 4; ++e)
                                C[(size_t)(row0 + e) * ND + col] = v[e];
                        }
            // ------------------------------ end job ------------------------------
        }
    }
}

// ---------------- fallback (only if ws too small): slow but correct ----------------
__global__ void tri_naive(const float* __restrict__ A, const float* __restrict__ B,
                          float* __restrict__ C) {
    int j = blockIdx.x * 64 + (threadIdx.x & 63);
    int i = blockIdx.y * 4 + (threadIdx.x >> 6);
    float s = 0.f;
    if (j >= i) {
        for (int k = i; k <= j; ++k) s += A[(size_t)i * ND + k] * B[(size_t)k * ND + j];
        C[(size_t)i * ND + j] = s;
    } else {
        C[(size_t)i * ND + j] = 0.f;
    }
}

extern "C" void kernel_launch(void* const* d_in, const int* in_sizes, int n_in,
                              void* d_out, int out_size, void* d_ws, size_t ws_size,
                              hipStream_t stream) {
    (void)in_sizes; (void)n_in; (void)out_size;
    const float* A = (const float*)d_in[0];
    const float* B = (const float*)d_in[1];
    float* C = (float*)d_out;

    const size_t halfws = (size_t)ND * ND * sizeof(unsigned short);  // 128 MiB
    if (ws_size >= 2 * halfws) {
        unsigned short* Aw = (unsigned short*)d_ws;
        unsigned short* Bt = (unsigned short*)((char*)d_ws + halfws);

        conv_a<<<dim3(ND * (ND / 8) / 256), dim3(256), 0, stream>>>(A, Aw);
        conv_bt<<<dim3(ND / 64, ND / 64), dim3(256), 0, stream>>>(B, Bt);
        zero_lower<<<dim3(2016), dim3(256), 0, stream>>>(C);
        gemm_tri8<<<dim3(256), dim3(512), 0, stream>>>(Aw, Bt, C);
    } else {
        tri_naive<<<dim3(ND / 64, ND / 4), dim3(256), 0, stream>>>(A, B, C);
    }
}

// Round 7
// 358.513 us; speedup vs baseline: 1.1222x; 1.1222x over previous
//
#include <hip/hip_runtime.h>
#include <hip/hip_bf16.h>
#include <stdint.h>

static constexpr int ND = 8192;

typedef __attribute__((ext_vector_type(8))) short bf16x8;
typedef __attribute__((ext_vector_type(4))) float f32x4;

#define GLOBAL_AS __attribute__((address_space(1)))
#define LDS_AS __attribute__((address_space(3)))

__device__ __forceinline__ void gld_lds16(const void* g, void* l) {
    __builtin_amdgcn_global_load_lds((const GLOBAL_AS void*)g, (LDS_AS void*)l, 16, 0, 0);
}

__device__ __forceinline__ unsigned short f2bf(float x) {
    union { float f; uint32_t u; } v; v.f = x;
    uint32_t u = v.u;
    uint32_t r = (u + 0x7fffu + ((u >> 16) & 1u)) >> 16;
    return (unsigned short)r;
}

// ---------------- pre-pass 1: Aw[i][k] = (k>=i) ? bf16(A[i][k]) : 0 ----------------
__global__ void conv_a(const float* __restrict__ A, unsigned short* __restrict__ Aw) {
    uint32_t g = blockIdx.x * 256u + threadIdx.x;
    int i  = (int)(g >> 10);
    int k0 = (int)(g & 1023u) << 3;
    if (k0 + 8 <= (i & ~255)) return;          // never read: k < (i>>8)*256
    const float* src = A + (size_t)i * ND + k0;
    float4 lo = *(const float4*)src;
    float4 hi = *(const float4*)(src + 4);
    float vals[8] = {lo.x, lo.y, lo.z, lo.w, hi.x, hi.y, hi.z, hi.w};
    unsigned short out[8];
#pragma unroll
    for (int e = 0; e < 8; ++e) {
        int k = k0 + e;
        out[e] = (k >= i) ? f2bf(vals[e]) : (unsigned short)0;
    }
    *(uint4*)(Aw + (size_t)i * ND + k0) = *(const uint4*)out;
}

// ------------- pre-pass 2: Bt[j][k] = (k<=j) ? bf16(B[k][j]) : 0 (transpose) -------------
__global__ void conv_bt(const float* __restrict__ B, unsigned short* __restrict__ Bt) {
    __shared__ float tile[64][65];
    int tk = blockIdx.x, tj = blockIdx.y;
    int t = threadIdx.x;
    int k0 = tk * 64, j0 = tj * 64;

    if (k0 > j0 + 63) {                         // tile wholly above diagonal (k > j)
        if (tk >= ((tj >> 2) + 1) * 4) return;  // beyond the 256-block: never read
        int jl = t >> 4;
        int kl = (t & 15) * 4;
#pragma unroll
        for (int r = 0; r < 4; ++r) {
            int j = j0 + jl + r * 16;
            *(uint2*)(Bt + (size_t)j * ND + k0 + kl) = make_uint2(0u, 0u);
        }
        return;
    }
    {   // load: coalesced in j
        int kl  = t >> 4;
        int jl4 = (t & 15) * 4;
#pragma unroll
        for (int r = 0; r < 4; ++r) {
            int k = k0 + kl + r * 16;
            float4 v = *(const float4*)(B + (size_t)k * ND + j0 + jl4);
            tile[kl + r * 16][jl4 + 0] = v.x;
            tile[kl + r * 16][jl4 + 1] = v.y;
            tile[kl + r * 16][jl4 + 2] = v.z;
            tile[kl + r * 16][jl4 + 3] = v.w;
        }
    }
    __syncthreads();
    {   // store: coalesced in k
        int jl  = t >> 4;
        int kl4 = (t & 15) * 4;
#pragma unroll
        for (int r = 0; r < 4; ++r) {
            int j = j0 + jl + r * 16;
            unsigned short o[4];
#pragma unroll
            for (int e = 0; e < 4; ++e) {
                int k = k0 + kl4 + e;
                float v = tile[kl4 + e][jl + r * 16];
                o[e] = (k <= j) ? f2bf(v) : (unsigned short)0;
            }
            *(uint2*)(Bt + (size_t)j * ND + k0 + kl4) = *(const uint2*)o;
        }
    }
}

// ------ zero-fill strictly-lower 128x128 tiles NOT covered by diagonal 256-blocks ------
__global__ __launch_bounds__(256) void zero_lower(float* __restrict__ C) {
    int bid = blockIdx.x;                        // 0 .. 2015
    int ti = (int)((1.0f + sqrtf(8.0f * (float)bid + 1.0f)) * 0.5f);
    while (ti * (ti + 1) / 2 <= bid) ++ti;
    while (ti * (ti - 1) / 2 > bid) --ti;
    int tj = bid - ti * (ti - 1) / 2;            // ti in [1,63], tj < ti
    if ((ti >> 1) == (tj >> 1)) return;          // covered by diagonal 256-tile GEMM
    int t = threadIdx.x;
    float* base = C + (size_t)(ti * 128) * ND + tj * 128;
    float4 z = {0.f, 0.f, 0.f, 0.f};
#pragma unroll
    for (int it = 0; it < 16; ++it) {
        int row = it * 8 + (t >> 5);
        *(float4*)(base + (size_t)row * ND + (t & 31) * 4) = z;
    }
}

// ------ zero-fill the 36 split (d>=24) 256x256 tiles (atomic accumulation targets) ------
__global__ __launch_bounds__(256) void zero_split(float* __restrict__ C) {
    int bid = blockIdx.x;                        // 0 .. 143
    int tile = bid >> 2, quad = bid & 3;
    int ti = 0, rem = tile;
    while (rem >= 8 - ti) { rem -= 8 - ti; ++ti; }  // rows 0..7, row ti has 8-ti splits
    int tjb = 31 - rem;                              // tj in [ti+24, 31]
    int t = threadIdx.x;
    float* base = C + (size_t)(ti * 256 + (quad >> 1) * 128) * ND
                    + tjb * 256 + (quad & 1) * 128;
    float4 z = {0.f, 0.f, 0.f, 0.f};
#pragma unroll
    for (int it = 0; it < 16; ++it) {
        int row = it * 8 + (t >> 5);
        *(float4*)(base + (size_t)row * ND + (t & 31) * 4) = z;
    }
}

// ========= main GEMM: 256x256 tiles, 8-phase pipeline, row-major patch order =========
#define BAR() __builtin_amdgcn_s_barrier()
#define WAIT_LGKM0() asm volatile("s_waitcnt lgkmcnt(0)" ::: "memory")
#define WAIT_VM4() asm volatile("s_waitcnt vmcnt(4)" ::: "memory")
#define WAIT_VM0() asm volatile("s_waitcnt vmcnt(0)" ::: "memory")
#define PRIO(x) __builtin_amdgcn_s_setprio(x)

#define LDA(BUF, MH) do { \
    _Pragma("unroll") for (int m_ = 0; m_ < 4; ++m_) \
    _Pragma("unroll") for (int kk_ = 0; kk_ < 2; ++kk_) \
        a_frag[m_][kk_] = *(const bf16x8*)(lds0 + (((BUF)*2 + 0)*2 + (MH))*8192 \
            + (a_lr + m_*16)*64 + (((kk_*4 + khi) ^ lanelo) << 3)); \
} while (0)

#define LDB(BUF, NH) do { \
    _Pragma("unroll") for (int n_ = 0; n_ < 2; ++n_) \
    _Pragma("unroll") for (int kk_ = 0; kk_ < 2; ++kk_) \
        b_frag[NH][n_][kk_] = *(const bf16x8*)(lds0 + (((BUF)*2 + 1)*2 + (NH))*8192 \
            + (b_lr + n_*16)*64 + (((kk_*4 + khi) ^ lanelo) << 3)); \
} while (0)

#define MM(MH, NH) do { \
    _Pragma("unroll") for (int kk_ = 0; kk_ < 2; ++kk_) \
    _Pragma("unroll") for (int m_ = 0; m_ < 4; ++m_) \
    _Pragma("unroll") for (int n_ = 0; n_ < 2; ++n_) \
        acc[(MH)*4 + m_][(NH)*2 + n_] = __builtin_amdgcn_mfma_f32_16x16x32_bf16( \
            a_frag[m_][kk_], b_frag[NH][n_][kk_], acc[(MH)*4 + m_][(NH)*2 + n_], 0, 0, 0); \
} while (0)

// Row-major enumeration (ti asc; within row tj DESC = longest-first). Same-row
// jobs have IDENTICAL k-start and march k in lockstep -> concurrent blocks share
// every A k-slice in L2/L3 (the locality dense GEMM gets for free). Tiles with
// d>=24 are split into two K-halves (both atomic, adjacent in the order).
__device__ __forceinline__ void job_map(int bid, int& tib, int& tjb, int& kt0,
                                        int& nkt, bool& atom) {
    int ti = 0, rem = bid;
    for (;;) {
        int ns = (ti < 8) ? (8 - ti) : 0;          // split tiles in this row
        int nj = (32 - ti) + ns;                   // jobs in this row
        if (rem < nj) {
            tib = ti;
            if (rem < 2 * ns) {                    // split half (d>=24)
                tjb = 31 - (rem >> 1);
                nkt = 2 * (tjb - ti + 1);          // 50..64 K-tiles, even
                kt0 = (rem & 1) * nkt;
                atom = true;
            } else {                               // unsplit (d<=23)
                int v = rem - 2 * ns;
                tjb = 31 - ns - v;
                nkt = 4 * (tjb - ti + 1);
                kt0 = 0;
                atom = false;
            }
            return;
        }
        rem -= nj;
        ++ti;
    }
}

__global__ __launch_bounds__(512, 2) void gemm_tri8(const unsigned short* __restrict__ Aw,
                                                    const unsigned short* __restrict__ Bt,
                                                    float* __restrict__ C) {
    int tib, tjb, kt0j, nkt;
    bool atom;
    job_map(blockIdx.x, tib, tjb, kt0j, nkt, atom);

    __shared__ __align__(16) unsigned short lds[2][2][2][128][64];
    unsigned short* lds0 = &lds[0][0][0][0][0];

    int t = threadIdx.x;
    int lane = t & 63, w = t >> 6;
    int wr = w >> 2, wc = w & 3;
    int lanelo = lane & 7, khi = lane >> 4;
    int a_lr = wr * 64 + (lane & 15);
    int b_lr = wc * 32 + (lane & 15);

    int kstart = tib * 256 + kt0j * 64;
    int nit = nkt >> 1;

    int srow = w * 8 + (lane >> 3);
    int sg = ((lane & 7) ^ (lane >> 3)) * 8;
    const unsigned short* gA = Aw + (size_t)(tib * 256 + srow) * ND + sg;
    const unsigned short* gB = Bt + (size_t)(tjb * 256 + srow) * ND + sg;
    unsigned short* sdst = lds0 + (w * 512 + lane * 8);

    auto STAGE = [&](int ab, int buf, int h, int ktg) {
        const unsigned short* g = (ab ? gB : gA) + (size_t)(h * 128) * ND + (kstart + ktg * 64);
        unsigned short* l = sdst + ((buf * 2 + ab) * 2 + h) * 8192;
        gld_lds16(g, l);
        gld_lds16(g + (size_t)64 * ND, l + 4096);
    };

    f32x4 acc[8][4];
#pragma unroll
    for (int m = 0; m < 8; ++m)
#pragma unroll
        for (int n = 0; n < 4; ++n) acc[m][n] = (f32x4){0.f, 0.f, 0.f, 0.f};

    bf16x8 a_frag[4][2];
    bf16x8 b_frag[2][2][2];

    // prologue: kt0 fully + kt1 A0,B0 (leave kt1's 2 half-tiles in flight)
    STAGE(0, 0, 0, 0); STAGE(1, 0, 0, 0); STAGE(0, 0, 1, 0); STAGE(1, 0, 1, 0);
    STAGE(0, 1, 0, 1); STAGE(1, 1, 0, 1);
    WAIT_VM4();
    BAR();

    for (int I = 0; I < nit; ++I) {
        int k1 = 2 * I + 1, k2 = 2 * I + 2, k3 = 2 * I + 3;
        bool s23 = (k2 < nkt);

        LDA(0, 0); LDB(0, 0);
        STAGE(0, 1, 1, k1);
        BAR(); WAIT_LGKM0(); PRIO(1); MM(0, 0); PRIO(0); BAR();
        LDB(0, 1);
        STAGE(1, 1, 1, k1);
        BAR(); WAIT_LGKM0(); PRIO(1); MM(0, 1); PRIO(0); BAR();
        LDA(0, 1);
        if (s23) STAGE(0, 0, 0, k2);
        BAR(); WAIT_LGKM0(); PRIO(1); MM(1, 0); PRIO(0); BAR();
        if (s23) STAGE(1, 0, 0, k2);
        BAR(); PRIO(1); MM(1, 1); PRIO(0);
        if (s23) { WAIT_VM4(); } else { WAIT_VM0(); }
        BAR();
        LDA(1, 0); LDB(1, 0);
        if (s23) STAGE(0, 0, 1, k2);
        BAR(); WAIT_LGKM0(); PRIO(1); MM(0, 0); PRIO(0); BAR();
        LDB(1, 1);
        if (s23) STAGE(1, 0, 1, k2);
        BAR(); WAIT_LGKM0(); PRIO(1); MM(0, 1); PRIO(0); BAR();
        LDA(1, 1);
        if (s23) STAGE(0, 1, 0, k3);
        BAR(); WAIT_LGKM0(); PRIO(1); MM(1, 0); PRIO(0); BAR();
        if (s23) STAGE(1, 1, 0, k3);
        BAR(); PRIO(1); MM(1, 1); PRIO(0); WAIT_VM4(); BAR();
    }

    // epilogue: C/D layout col=lane&15, row=(lane>>4)*4+e
#pragma unroll
    for (int mh = 0; mh < 2; ++mh)
#pragma unroll
        for (int m = 0; m < 4; ++m)
#pragma unroll
            for (int nh = 0; nh < 2; ++nh)
#pragma unroll
                for (int n = 0; n < 2; ++n) {
                    f32x4 v = acc[mh * 4 + m][nh * 2 + n];
                    int row0 = tib * 256 + mh * 128 + wr * 64 + m * 16 + (lane >> 4) * 4;
                    int col  = tjb * 256 + nh * 128 + wc * 32 + n * 16 + (lane & 15);
                    if (atom) {
#pragma unroll
                        for (int e = 0; e < 4; ++e)
                            atomicAdd(&C[(size_t)(row0 + e) * ND + col], v[e]);
                    } else {
#pragma unroll
                        for (int e = 0; e < 4; ++e)
                            C[(size_t)(row0 + e) * ND + col] = v[e];
                    }
                }
}

// ---------------- fallback (only if ws too small): slow but correct ----------------
__global__ void tri_naive(const float* __restrict__ A, const float* __restrict__ B,
                          float* __restrict__ C) {
    int j = blockIdx.x * 64 + (threadIdx.x & 63);
    int i = blockIdx.y * 4 + (threadIdx.x >> 6);
    float s = 0.f;
    if (j >= i) {
        for (int k = i; k <= j; ++k) s += A[(size_t)i * ND + k] * B[(size_t)k * ND + j];
        C[(size_t)i * ND + j] = s;
    } else {
        C[(size_t)i * ND + j] = 0.f;
    }
}

extern "C" void kernel_launch(void* const* d_in, const int* in_sizes, int n_in,
                              void* d_out, int out_size, void* d_ws, size_t ws_size,
                              hipStream_t stream) {
    (void)in_sizes; (void)n_in; (void)out_size;
    const float* A = (const float*)d_in[0];
    const float* B = (const float*)d_in[1];
    float* C = (float*)d_out;

    const size_t halfws = (size_t)ND * ND * sizeof(unsigned short);  // 128 MiB
    if (ws_size >= 2 * halfws) {
        unsigned short* Aw = (unsigned short*)d_ws;
        unsigned short* Bt = (unsigned short*)((char*)d_ws + halfws);

        conv_a<<<dim3(ND * (ND / 8) / 256), dim3(256), 0, stream>>>(A, Aw);
        conv_bt<<<dim3(ND / 64, ND / 64), dim3(256), 0, stream>>>(B, Bt);
        zero_lower<<<dim3(2016), dim3(256), 0, stream>>>(C);
        zero_split<<<dim3(144), dim3(256), 0, stream>>>(C);
        // 564 jobs: 528 tiles - 36 split + 72 halves, row-major patch order
        gemm_tri8<<<dim3(564), dim3(512), 0, stream>>>(Aw, Bt, C);
    } else {
        tri_naive<<<dim3(ND / 64, ND / 4), dim3(256), 0, stream>>>(A, B, C);
    }
}

// Round 8
// 333.617 us; speedup vs baseline: 1.2060x; 1.0746x over previous
//
#include <hip/hip_runtime.h>
#include <hip/hip_bf16.h>
#include <stdint.h>

static constexpr int ND = 8192;

typedef __attribute__((ext_vector_type(8))) short bf16x8;
typedef __attribute__((ext_vector_type(4))) float f32x4;

#define GLOBAL_AS __attribute__((address_space(1)))
#define LDS_AS __attribute__((address_space(3)))

__device__ __forceinline__ void gld_lds16(const void* g, void* l) {
    __builtin_amdgcn_global_load_lds((const GLOBAL_AS void*)g, (LDS_AS void*)l, 16, 0, 0);
}

__device__ __forceinline__ unsigned short f2bf(float x) {
    union { float f; uint32_t u; } v; v.f = x;
    uint32_t u = v.u;
    uint32_t r = (u + 0x7fffu + ((u >> 16) & 1u)) >> 16;
    return (unsigned short)r;
}

// ---------------- pre-pass 1: Aw[i][k] = (k>=i) ? bf16(A[i][k]) : 0 ----------------
// Input reads nontemporal (read-once); output stores cacheable (re-read by gemm).
__global__ void conv_a(const float* __restrict__ A, unsigned short* __restrict__ Aw) {
    uint32_t g = blockIdx.x * 256u + threadIdx.x;
    int i  = (int)(g >> 10);
    int k0 = (int)(g & 1023u) << 3;
    if (k0 + 8 <= (i & ~255)) return;          // never read: k < (i>>8)*256
    const float* src = A + (size_t)i * ND + k0;
    f32x4 lo = __builtin_nontemporal_load((const f32x4*)src);
    f32x4 hi = __builtin_nontemporal_load((const f32x4*)(src + 4));
    float vals[8] = {lo[0], lo[1], lo[2], lo[3], hi[0], hi[1], hi[2], hi[3]};
    unsigned short out[8];
#pragma unroll
    for (int e = 0; e < 8; ++e) {
        int k = k0 + e;
        out[e] = (k >= i) ? f2bf(vals[e]) : (unsigned short)0;
    }
    *(uint4*)(Aw + (size_t)i * ND + k0) = *(const uint4*)out;
}

// ------------- pre-pass 2: Bt[j][k] = (k<=j) ? bf16(B[k][j]) : 0 (transpose) -------------
__global__ void conv_bt(const float* __restrict__ B, unsigned short* __restrict__ Bt) {
    __shared__ float tile[64][65];
    int tk = blockIdx.x, tj = blockIdx.y;
    int t = threadIdx.x;
    int k0 = tk * 64, j0 = tj * 64;

    if (k0 > j0 + 63) {                         // tile wholly above diagonal (k > j)
        if (tk >= ((tj >> 2) + 1) * 4) return;  // beyond the 256-block: never read
        int jl = t >> 4;
        int kl = (t & 15) * 4;
#pragma unroll
        for (int r = 0; r < 4; ++r) {
            int j = j0 + jl + r * 16;
            *(uint2*)(Bt + (size_t)j * ND + k0 + kl) = make_uint2(0u, 0u);
        }
        return;
    }
    {   // load: coalesced in j, nontemporal (read-once)
        int kl  = t >> 4;
        int jl4 = (t & 15) * 4;
#pragma unroll
        for (int r = 0; r < 4; ++r) {
            int k = k0 + kl + r * 16;
            f32x4 v = __builtin_nontemporal_load(
                (const f32x4*)(B + (size_t)k * ND + j0 + jl4));
            tile[kl + r * 16][jl4 + 0] = v[0];
            tile[kl + r * 16][jl4 + 1] = v[1];
            tile[kl + r * 16][jl4 + 2] = v[2];
            tile[kl + r * 16][jl4 + 3] = v[3];
        }
    }
    __syncthreads();
    {   // store: coalesced in k (cacheable — re-read by gemm)
        int jl  = t >> 4;
        int kl4 = (t & 15) * 4;
#pragma unroll
        for (int r = 0; r < 4; ++r) {
            int j = j0 + jl + r * 16;
            unsigned short o[4];
#pragma unroll
            for (int e = 0; e < 4; ++e) {
                int k = k0 + kl4 + e;
                float v = tile[kl4 + e][jl + r * 16];
                o[e] = (k <= j) ? f2bf(v) : (unsigned short)0;
            }
            *(uint2*)(Bt + (size_t)j * ND + k0 + kl4) = *(const uint2*)o;
        }
    }
}

// ------ zero-fill strictly-lower 128x128 tiles NOT covered by diagonal 256-blocks ------
// Runs FIRST (before convs) so its writes can't evict Aw/Bt panels; stores nontemporal.
__global__ __launch_bounds__(256) void zero_lower(float* __restrict__ C) {
    int bid = blockIdx.x;                        // 0 .. 2015
    int ti = (int)((1.0f + sqrtf(8.0f * (float)bid + 1.0f)) * 0.5f);
    while (ti * (ti + 1) / 2 <= bid) ++ti;
    while (ti * (ti - 1) / 2 > bid) --ti;
    int tj = bid - ti * (ti - 1) / 2;            // ti in [1,63], tj < ti
    if ((ti >> 1) == (tj >> 1)) return;          // covered by diagonal 256-tile GEMM
    int t = threadIdx.x;
    float* base = C + (size_t)(ti * 128) * ND + tj * 128;
    f32x4 z = {0.f, 0.f, 0.f, 0.f};
#pragma unroll
    for (int it = 0; it < 16; ++it) {
        int row = it * 8 + (t >> 5);
        __builtin_nontemporal_store(z, (f32x4*)(base + (size_t)row * ND + (t & 31) * 4));
    }
}

// ===== main GEMM: 256x256 tiles, 8-phase pipeline, LPT order (R3 exact) =====
#define BAR() __builtin_amdgcn_s_barrier()
#define WAIT_LGKM0() asm volatile("s_waitcnt lgkmcnt(0)" ::: "memory")
#define WAIT_VM4() asm volatile("s_waitcnt vmcnt(4)" ::: "memory")
#define WAIT_VM0() asm volatile("s_waitcnt vmcnt(0)" ::: "memory")
#define PRIO(x) __builtin_amdgcn_s_setprio(x)

#define LDA(BUF, MH) do { \
    _Pragma("unroll") for (int m_ = 0; m_ < 4; ++m_) \
    _Pragma("unroll") for (int kk_ = 0; kk_ < 2; ++kk_) \
        a_frag[m_][kk_] = *(const bf16x8*)(lds0 + (((BUF)*2 + 0)*2 + (MH))*8192 \
            + (a_lr + m_*16)*64 + (((kk_*4 + khi) ^ lanelo) << 3)); \
} while (0)

#define LDB(BUF, NH) do { \
    _Pragma("unroll") for (int n_ = 0; n_ < 2; ++n_) \
    _Pragma("unroll") for (int kk_ = 0; kk_ < 2; ++kk_) \
        b_frag[NH][n_][kk_] = *(const bf16x8*)(lds0 + (((BUF)*2 + 1)*2 + (NH))*8192 \
            + (b_lr + n_*16)*64 + (((kk_*4 + khi) ^ lanelo) << 3)); \
} while (0)

#define MM(MH, NH) do { \
    _Pragma("unroll") for (int kk_ = 0; kk_ < 2; ++kk_) \
    _Pragma("unroll") for (int m_ = 0; m_ < 4; ++m_) \
    _Pragma("unroll") for (int n_ = 0; n_ < 2; ++n_) \
        acc[(MH)*4 + m_][(NH)*2 + n_] = __builtin_amdgcn_mfma_f32_16x16x32_bf16( \
            a_frag[m_][kk_], b_frag[NH][n_][kk_], acc[(MH)*4 + m_][(NH)*2 + n_], 0, 0, 0); \
} while (0)

__global__ __launch_bounds__(512, 2) void gemm_tri8(const unsigned short* __restrict__ Aw,
                                                    const unsigned short* __restrict__ Bt,
                                                    float* __restrict__ C) {
    int bid = blockIdx.x;                        // 0 .. 527, longest-K first (LPT)
    int s = (int)((sqrtf(8.0f * (float)bid + 1.0f) - 1.0f) * 0.5f);
    while ((s + 1) * (s + 2) / 2 <= bid) ++s;
    while (s * (s + 1) / 2 > bid) --s;
    int tib = bid - s * (s + 1) / 2;
    int tjb = tib + (31 - s);

    __shared__ __align__(16) unsigned short lds[2][2][2][128][64];
    unsigned short* lds0 = &lds[0][0][0][0][0];

    int t = threadIdx.x;
    int lane = t & 63, w = t >> 6;
    int wr = w >> 2, wc = w & 3;
    int lanelo = lane & 7, khi = lane >> 4;
    int a_lr = wr * 64 + (lane & 15);
    int b_lr = wc * 32 + (lane & 15);

    int kstart = tib * 256;
    int nkt = (tjb - tib + 1) * 4;
    int nit = nkt >> 1;

    int srow = w * 8 + (lane >> 3);
    int sg = ((lane & 7) ^ (lane >> 3)) * 8;
    const unsigned short* gA = Aw + (size_t)(tib * 256 + srow) * ND + sg;
    const unsigned short* gB = Bt + (size_t)(tjb * 256 + srow) * ND + sg;
    unsigned short* sdst = lds0 + (w * 512 + lane * 8);

    auto STAGE = [&](int ab, int buf, int h, int ktg) {
        const unsigned short* g = (ab ? gB : gA) + (size_t)(h * 128) * ND + (kstart + ktg * 64);
        unsigned short* l = sdst + ((buf * 2 + ab) * 2 + h) * 8192;
        gld_lds16(g, l);
        gld_lds16(g + (size_t)64 * ND, l + 4096);
    };

    f32x4 acc[8][4];
#pragma unroll
    for (int m = 0; m < 8; ++m)
#pragma unroll
        for (int n = 0; n < 4; ++n) acc[m][n] = (f32x4){0.f, 0.f, 0.f, 0.f};

    bf16x8 a_frag[4][2];
    bf16x8 b_frag[2][2][2];

    // prologue: kt0 fully + kt1 A0,B0 (leave kt1's 2 half-tiles in flight)
    STAGE(0, 0, 0, 0); STAGE(1, 0, 0, 0); STAGE(0, 0, 1, 0); STAGE(1, 0, 1, 0);
    STAGE(0, 1, 0, 1); STAGE(1, 1, 0, 1);
    WAIT_VM4();
    BAR();

    for (int I = 0; I < nit; ++I) {
        int k1 = 2 * I + 1, k2 = 2 * I + 2, k3 = 2 * I + 3;
        bool s23 = (k2 < nkt);

        LDA(0, 0); LDB(0, 0);
        STAGE(0, 1, 1, k1);
        BAR(); WAIT_LGKM0(); PRIO(1); MM(0, 0); PRIO(0); BAR();
        LDB(0, 1);
        STAGE(1, 1, 1, k1);
        BAR(); WAIT_LGKM0(); PRIO(1); MM(0, 1); PRIO(0); BAR();
        LDA(0, 1);
        if (s23) STAGE(0, 0, 0, k2);
        BAR(); WAIT_LGKM0(); PRIO(1); MM(1, 0); PRIO(0); BAR();
        if (s23) STAGE(1, 0, 0, k2);
        BAR(); PRIO(1); MM(1, 1); PRIO(0);
        if (s23) { WAIT_VM4(); } else { WAIT_VM0(); }
        BAR();
        LDA(1, 0); LDB(1, 0);
        if (s23) STAGE(0, 0, 1, k2);
        BAR(); WAIT_LGKM0(); PRIO(1); MM(0, 0); PRIO(0); BAR();
        LDB(1, 1);
        if (s23) STAGE(1, 0, 1, k2);
        BAR(); WAIT_LGKM0(); PRIO(1); MM(0, 1); PRIO(0); BAR();
        LDA(1, 1);
        if (s23) STAGE(0, 1, 0, k3);
        BAR(); WAIT_LGKM0(); PRIO(1); MM(1, 0); PRIO(0); BAR();
        if (s23) STAGE(1, 1, 0, k3);
        BAR(); PRIO(1); MM(1, 1); PRIO(0); WAIT_VM4(); BAR();
    }

    // epilogue: C/D layout col=lane&15, row=(lane>>4)*4+e — nontemporal stores
    // (C is never re-read; keep L3 for the Aw/Bt panels)
#pragma unroll
    for (int mh = 0; mh < 2; ++mh)
#pragma unroll
        for (int m = 0; m < 4; ++m)
#pragma unroll
            for (int nh = 0; nh < 2; ++nh)
#pragma unroll
                for (int n = 0; n < 2; ++n) {
                    f32x4 v = acc[mh * 4 + m][nh * 2 + n];
                    int row0 = tib * 256 + mh * 128 + wr * 64 + m * 16 + (lane >> 4) * 4;
                    int col  = tjb * 256 + nh * 128 + wc * 32 + n * 16 + (lane & 15);
#pragma unroll
                    for (int e = 0; e < 4; ++e)
                        __builtin_nontemporal_store(
                            v[e], &C[(size_t)(row0 + e) * ND + col]);
                }
}

// ---------------- fallback (only if ws too small): slow but correct ----------------
__global__ void tri_naive(const float* __restrict__ A, const float* __restrict__ B,
                          float* __restrict__ C) {
    int j = blockIdx.x * 64 + (threadIdx.x & 63);
    int i = blockIdx.y * 4 + (threadIdx.x >> 6);
    float s = 0.f;
    if (j >= i) {
        for (int k = i; k <= j; ++k) s += A[(size_t)i * ND + k] * B[(size_t)k * ND + j];
        C[(size_t)i * ND + j] = s;
    } else {
        C[(size_t)i * ND + j] = 0.f;
    }
}

extern "C" void kernel_launch(void* const* d_in, const int* in_sizes, int n_in,
                              void* d_out, int out_size, void* d_ws, size_t ws_size,
                              hipStream_t stream) {
    (void)in_sizes; (void)n_in; (void)out_size;
    const float* A = (const float*)d_in[0];
    const float* B = (const float*)d_in[1];
    float* C = (float*)d_out;

    const size_t halfws = (size_t)ND * ND * sizeof(unsigned short);  // 128 MiB
    if (ws_size >= 2 * halfws) {
        unsigned short* Aw = (unsigned short*)d_ws;
        unsigned short* Bt = (unsigned short*)((char*)d_ws + halfws);

        // zero-fill FIRST so its write traffic can't evict conv outputs from L2/L3
        zero_lower<<<dim3(2016), dim3(256), 0, stream>>>(C);
        conv_a<<<dim3(ND * (ND / 8) / 256), dim3(256), 0, stream>>>(A, Aw);
        conv_bt<<<dim3(ND / 64, ND / 64), dim3(256), 0, stream>>>(B, Bt);
        gemm_tri8<<<dim3(528), dim3(512), 0, stream>>>(Aw, Bt, C);
    } else {
        tri_naive<<<dim3(ND / 64, ND / 4), dim3(256), 0, stream>>>(A, B, C);
    }
}